// Round 6
// baseline (1355.238 us; speedup 1.0000x reference)
//
#include <hip/hip_runtime.h>
#include <stdint.h>

// ---------------------------------------------------------------------------
// GlobalMetaAggregator  R=2,K=3,N=16384,V=256,E=1,L=8,VE=128,LK=1,OUT=64,
// IN=256,HID=512,C=5.
// Round 6: (1) mgemm staging via __builtin_amdgcn_global_load_lds width=16
// (m93->m97 ladder step) with unpadded linear LDS tiles; (2) extra-channel
// pool fused into the me-GEMM epilogue (me never hits HBM); (3) ln2_pool +
// gpool fused per-node; LN kernels vectorized to 16B/lane (320-thr blocks).
// ---------------------------------------------------------------------------

typedef unsigned short bf16_t;
using ushort8v = __attribute__((ext_vector_type(8))) unsigned short;
using bf16x8   = __attribute__((ext_vector_type(8))) __bf16;
using f32x4    = __attribute__((ext_vector_type(4))) float;

__device__ __forceinline__ float bf2f(bf16_t u) {
    return __uint_as_float(((unsigned int)u) << 16);
}
__device__ __forceinline__ bf16_t f2bf(float f) {
    unsigned int u = __float_as_uint(f);
    u += 0x7FFFu + ((u >> 16) & 1u);   // RNE
    return (bf16_t)(u >> 16);
}
__device__ __forceinline__ float ld1(const void* p, long i, int dt) {
    return dt ? bf2f(((const bf16_t*)p)[i]) : ((const float*)p)[i];
}
__device__ __forceinline__ float4 ld4(const void* p, long i, int dt) {
    if (dt) {
        ushort4 v = *(const ushort4*)((const bf16_t*)p + i);
        return make_float4(bf2f(v.x), bf2f(v.y), bf2f(v.z), bf2f(v.w));
    }
    return *(const float4*)((const float*)p + i);
}
__device__ __forceinline__ ushort8v ld8bf(const void* p, long i, int dt) {
    if (dt) return *(const ushort8v*)((const bf16_t*)p + i);
    const float* f = (const float*)p + i;
    float4 a = *(const float4*)f, b = *(const float4*)(f + 4);
    ushort8v r;
    r[0] = f2bf(a.x); r[1] = f2bf(a.y); r[2] = f2bf(a.z); r[3] = f2bf(a.w);
    r[4] = f2bf(b.x); r[5] = f2bf(b.y); r[6] = f2bf(b.z); r[7] = f2bf(b.w);
    return r;
}
__device__ __forceinline__ float decode_scalar(const void* p, int isbf) {
    if (!isbf) return *(const float*)p;
    unsigned int u = *(const unsigned int*)p;
    if ((u & 0xFFFFu) == 0u) return __uint_as_float(u);
    return bf2f((bf16_t)(u & 0xFFFFu));
}
__device__ __forceinline__ float wave_reduce(float v) {
#pragma unroll
    for (int o = 32; o > 0; o >>= 1) v += __shfl_down(v, o, 64);
    return v;
}
// async global->LDS, 16B per lane; LDS dest = l + lane*16 (linear).
__device__ __forceinline__ void gl2lds16(const void* g, void* l) {
    using gptr_t = const __attribute__((address_space(1))) unsigned int*;
    using lptr_t = __attribute__((address_space(3))) unsigned int*;
    __builtin_amdgcn_global_load_lds((gptr_t)(uintptr_t)g, (lptr_t)(uintptr_t)l,
                                     16, 0, 0);
}

// ---------------------------------------------------------------------------
__global__ void detect_k(const unsigned int* __restrict__ w, long nwords,
                         int* __restrict__ flag)
{
    const int lane = threadIdx.x;
    long idx = (long)lane * 997 + 13;
    if (idx >= nwords) idx = lane % (nwords > 0 ? nwords : 1);
    unsigned int word = w[idx];
    int e = (word >> 7) & 0xFF;
    int vote = (e >= 110 && e <= 134) ? 1 : 0;
    unsigned long long m = __ballot(vote);
    if (lane == 0) *flag = (__popcll(m) >= 32) ? 1 : 0;
}

// ---------------------------------------------------------------------------
// transpose: in [K][N] (flag dtype) -> out [N][K] bf16, batched over z
// ---------------------------------------------------------------------------
__global__ __launch_bounds__(256) void transT_k(
    const void* __restrict__ in, long inoff, long sInZ, int Kd, int Nd,
    bf16_t* __restrict__ out, long outoff, long sOutZ,
    const int* __restrict__ flag)
{
    const int isbf = *flag;
    const long z = blockIdx.z;
    long idx = (long)blockIdx.x * 256 + threadIdx.x;
    if (idx >= (long)Kd * Nd) return;
    int k = (int)(idx / Nd), n = (int)(idx % Nd);
    out[outoff + z * sOutZ + (long)n * Kd + k] =
        f2bf(ld1(in, inoff + z * sInZ + idx, isbf));
}

// ---------------------------------------------------------------------------
// fold GEMM (small): CT = (A@B)^T bf16.  A [M][K], B [K][N] flag dtype.
// ---------------------------------------------------------------------------
__global__ __launch_bounds__(256) void fold_gemmT_k(
    const void* __restrict__ A, long aoff, long sAz, int lda,
    const void* __restrict__ B, long boff, long sBz, int ldb,
    bf16_t* __restrict__ CT, long coff, long sCz, int ldcT,
    int K, const int* __restrict__ flag)
{
    const int isbf = *flag;
    __shared__ __align__(16) float As[16][68];
    __shared__ __align__(16) float Bs[16][68];
    const int z = blockIdx.z, t = threadIdx.x;
    const int tx = t & 15, ty = t >> 4;
    const int am = t >> 2, ak = (t & 3) << 2;
    const int bn = tx << 2;
    const long aBase = aoff + z * sAz + (long)(blockIdx.y * 64 + am) * lda + ak;
    const long bBase = boff + z * sBz + (long)ty * ldb + blockIdx.x * 64 + bn;
    float acc[4][4] = {};
    for (int k0 = 0; k0 < K; k0 += 16) {
        float4 av = ld4(A, aBase + k0, isbf);
        float4 bv = ld4(B, bBase + (long)k0 * ldb, isbf);
        __syncthreads();
        As[ak + 0][am] = av.x; As[ak + 1][am] = av.y;
        As[ak + 2][am] = av.z; As[ak + 3][am] = av.w;
        *(float4*)&Bs[ty][bn] = bv;
        __syncthreads();
#pragma unroll
        for (int k = 0; k < 16; k++) {
            float4 a4 = *(const float4*)&As[k][ty << 2];
            float4 b4 = *(const float4*)&Bs[k][tx << 2];
            float ar[4] = {a4.x, a4.y, a4.z, a4.w};
            float br[4] = {b4.x, b4.y, b4.z, b4.w};
#pragma unroll
            for (int i = 0; i < 4; i++)
#pragma unroll
                for (int j = 0; j < 4; j++) acc[i][j] += ar[i] * br[j];
        }
    }
    const int cm = blockIdx.y * 64 + (ty << 2);
    const int cn = blockIdx.x * 64 + (tx << 2);
#pragma unroll
    for (int i = 0; i < 4; i++)
#pragma unroll
        for (int j = 0; j < 4; j++)
            CT[coff + z * sCz + (long)(cn + j) * ldcT + (cm + i)] = f2bf(acc[i][j]);
}

// ---------------------------------------------------------------------------
// MFMA GEMM with global_load_lds staging.
// C[z] = A[z] @ BT[z]^T (+bias)(+PReLU), f32 accumulate.
// zq=z/zdiv, zr=z%zdiv; offset = off + zq*s1 + zr*s2.
// A [M][K] (adt 0=f32,1=bf16,2=flag), BT [N][K] bf16. LDS rows = 32 ushorts.
// Tile 128 x BN_, BK=32, 4 waves (2x2), wave tile 64 x WNW_.
// ---------------------------------------------------------------------------
template <int BN_, int WNW_, int MODE, int CD>
__global__ __launch_bounds__(256) void mgemm(
    const void* __restrict__ A, int adt, long aoff, long sA1, long sA2, int lda,
    const bf16_t* __restrict__ BT, long boff, long sB1, long sB2,
    void* __restrict__ C, long coff, long sC1, long sC2, int ldc,
    const void* __restrict__ bias, long biasoff, long sBi1, long sBi2,
    const void* __restrict__ alpha_ptr, int K, int zdiv,
    const int* __restrict__ flag)
{
    constexpr int NJ = WNW_ / 16;
    const int isbf = *flag;
    const int adt_ = (adt == 2) ? isbf : adt;
    const int cdt = (CD == 2) ? isbf : 1;

    __shared__ __align__(16) bf16_t As[128 * 32];
    __shared__ __align__(16) bf16_t Bs[BN_ * 32];

    const int t = threadIdx.x;
    const int lane = t & 63, wv = t >> 6;
    const int quad = lane >> 4, r16 = lane & 15;
    const int wy = wv >> 1, wxx = wv & 1;
    const int srow = lane >> 2;          // DMA: row within 16-row issue
    const int scol = (lane & 3) * 8;     // DMA: ushort col offset
    const int z = blockIdx.z;
    const int zq = z / zdiv, zr = z % zdiv;
    const long blockM = (long)blockIdx.y * 128;
    const int  blockN = blockIdx.x * BN_;

    f32x4 acc[4][NJ];
    const f32x4 zero4 = {0.f, 0.f, 0.f, 0.f};
#pragma unroll
    for (int i = 0; i < 4; i++)
#pragma unroll
        for (int j = 0; j < NJ; j++) acc[i][j] = zero4;

    const long aBase = aoff + zq * sA1 + zr * sA2;
    const long bBase = boff + zq * sB1 + zr * sB2;

    for (int k0 = 0; k0 < K; k0 += 32) {
        __syncthreads();   // prior-iter LDS readers done
        if (adt_) {
#pragma unroll
            for (int s = 0; s < 2; s++) {
                int rbase = wv * 32 + s * 16;
                const bf16_t* g = (const bf16_t*)A + aBase
                    + (blockM + rbase + srow) * (long)lda + k0 + scol;
                gl2lds16(g, &As[rbase * 32]);
            }
        } else {
#pragma unroll
            for (int c = 0; c < 2; c++) {
                int lin = t + c * 256;
                int m = lin >> 2, kq = (lin & 3) * 8;
                ushort8v v = ld8bf(A, aBase + (blockM + m) * (long)lda + k0 + kq, 0);
                *(ushort8v*)&As[m * 32 + kq] = v;
            }
        }
#pragma unroll
        for (int s = 0; s < BN_ / 64; s++) {
            int rbase = wv * (BN_ / 4) + s * 16;
            const bf16_t* g = BT + bBase
                + (long)(blockN + rbase + srow) * K + k0 + scol;
            gl2lds16(g, &Bs[rbase * 32]);
        }
        __syncthreads();   // drains vmcnt (DMA) + lgkm

        bf16x8 af[4], bfr[NJ];
#pragma unroll
        for (int i = 0; i < 4; i++)
            af[i] = __builtin_bit_cast(bf16x8,
                *(const ushort8v*)&As[(wy * 64 + i * 16 + r16) * 32 + quad * 8]);
#pragma unroll
        for (int j = 0; j < NJ; j++)
            bfr[j] = __builtin_bit_cast(bf16x8,
                *(const ushort8v*)&Bs[(wxx * WNW_ + j * 16 + r16) * 32 + quad * 8]);
#pragma unroll
        for (int i = 0; i < 4; i++)
#pragma unroll
            for (int j = 0; j < NJ; j++)
                acc[i][j] = __builtin_amdgcn_mfma_f32_16x16x32_bf16(
                    af[i], bfr[j], acc[i][j], 0, 0, 0);
    }

    const float alpha = (MODE == 2) ? decode_scalar(alpha_ptr, isbf) : 0.f;
    const long cBase = coff + zq * sC1 + zr * sC2;
#pragma unroll
    for (int j = 0; j < NJ; j++) {
        const int n = blockN + wxx * WNW_ + j * 16 + r16;
        const float bz = (MODE >= 1)
            ? ld1(bias, biasoff + zq * sBi1 + zr * sBi2 + n, isbf) : 0.f;
#pragma unroll
        for (int i = 0; i < 4; i++) {
            const long m0 = blockM + wy * 64 + i * 16 + quad * 4;
#pragma unroll
            for (int rg = 0; rg < 4; rg++) {
                float v = acc[i][j][rg] + bz;
                if (MODE == 2) v = (v >= 0.f) ? v : alpha * v;
                const long off = cBase + (m0 + rg) * (long)ldc + n;
                if (cdt) ((bf16_t*)C)[off] = f2bf(v);
                else     ((float*)C)[off] = v;
            }
        }
    }
}

// ---------------------------------------------------------------------------
// Fused extra-channel GEMM + sigmoid-softmax pool.
// Per block: 128 me-rows (16 nodes x L=8) x 256 cols, K=128.
// me = extra @ eT^T kept in accumulators; pool over L -> EO bf16 [Nc][256].
// grid (1, Nc/16, 2=relation).
// ---------------------------------------------------------------------------
__global__ __launch_bounds__(256) void megemm_pool(
    const void* __restrict__ A, long aoff, long sAr,          // extra, flag dtype
    const bf16_t* __restrict__ BT, long sBr,                  // eT [256][128]
    const void* __restrict__ wx,
    bf16_t* __restrict__ EO, long sEOr,
    const int* __restrict__ flag)
{
    const int isbf = *flag;
    __shared__ __align__(16) bf16_t As[128 * 32];
    __shared__ __align__(16) bf16_t Bs[256 * 32];
    __shared__ float sred[128][2];
    __shared__ float gvs[128];

    const int t = threadIdx.x;
    const int lane = t & 63, wv = t >> 6;
    const int quad = lane >> 4, r16 = lane & 15;
    const int wy = wv >> 1, wxx = wv & 1;
    const int srow = lane >> 2, scol = (lane & 3) * 8;
    const int r = blockIdx.z;
    const long blockM = (long)blockIdx.y * 128;

    f32x4 acc[4][8];
    const f32x4 zero4 = {0.f, 0.f, 0.f, 0.f};
#pragma unroll
    for (int i = 0; i < 4; i++)
#pragma unroll
        for (int j = 0; j < 8; j++) acc[i][j] = zero4;

    const long aBase = aoff + (long)r * sAr;
    const long bBase = (long)r * sBr;

    for (int k0 = 0; k0 < 128; k0 += 32) {
        __syncthreads();
        if (isbf) {
#pragma unroll
            for (int s = 0; s < 2; s++) {
                int rbase = wv * 32 + s * 16;
                const bf16_t* g = (const bf16_t*)A + aBase
                    + (blockM + rbase + srow) * 128L + k0 + scol;
                gl2lds16(g, &As[rbase * 32]);
            }
        } else {
#pragma unroll
            for (int c = 0; c < 2; c++) {
                int lin = t + c * 256;
                int m = lin >> 2, kq = (lin & 3) * 8;
                ushort8v v = ld8bf(A, aBase + (blockM + m) * 128L + k0 + kq, 0);
                *(ushort8v*)&As[m * 32 + kq] = v;
            }
        }
#pragma unroll
        for (int s = 0; s < 4; s++) {
            int rbase = wv * 64 + s * 16;
            const bf16_t* g = BT + bBase + (long)(rbase + srow) * 128 + k0 + scol;
            gl2lds16(g, &Bs[rbase * 32]);
        }
        __syncthreads();

        bf16x8 af[4], bfr[8];
#pragma unroll
        for (int i = 0; i < 4; i++)
            af[i] = __builtin_bit_cast(bf16x8,
                *(const ushort8v*)&As[(wy * 64 + i * 16 + r16) * 32 + quad * 8]);
#pragma unroll
        for (int j = 0; j < 8; j++)
            bfr[j] = __builtin_bit_cast(bf16x8,
                *(const ushort8v*)&Bs[(wxx * 128 + j * 16 + r16) * 32 + quad * 8]);
#pragma unroll
        for (int i = 0; i < 4; i++)
#pragma unroll
            for (int j = 0; j < 8; j++)
                acc[i][j] = __builtin_amdgcn_mfma_f32_16x16x32_bf16(
                    af[i], bfr[j], acc[i][j], 0, 0, 0);
    }

    // ---- pool: p[row] = dot(me[row,:], wx) ----
    float wxv[8];
#pragma unroll
    for (int j = 0; j < 8; j++)
        wxv[j] = ld1(wx, wxx * 128 + j * 16 + r16, isbf);

    float pp[4][4];
#pragma unroll
    for (int i = 0; i < 4; i++)
#pragma unroll
        for (int rg = 0; rg < 4; rg++) {
            float s = 0.f;
#pragma unroll
            for (int j = 0; j < 8; j++) s += acc[i][j][rg] * wxv[j];
            pp[i][rg] = s;
        }
#pragma unroll
    for (int o = 1; o < 16; o <<= 1)
#pragma unroll
        for (int i = 0; i < 4; i++)
#pragma unroll
            for (int rg = 0; rg < 4; rg++)
                pp[i][rg] += __shfl_xor(pp[i][rg], o, 64);
    if (r16 == 0) {
#pragma unroll
        for (int i = 0; i < 4; i++)
#pragma unroll
            for (int rg = 0; rg < 4; rg++)
                sred[wy * 64 + i * 16 + quad * 4 + rg][wxx] = pp[i][rg];
    }
    __syncthreads();
    if (t < 16) {   // 16 nodes: softmax(sigmoid(score)) over L=8
        float e[8], sm = 0.f;
#pragma unroll
        for (int l = 0; l < 8; l++) {
            float sc = sred[t * 8 + l][0] + sred[t * 8 + l][1];
            float sg = 1.f / (1.f + expf(-sc));
            e[l] = expf(sg); sm += e[l];
        }
        float inv = 1.f / sm;
#pragma unroll
        for (int l = 0; l < 8; l++) gvs[t * 8 + l] = e[l] * inv;
    }
    __syncthreads();

    float gvl[4][4];
#pragma unroll
    for (int i = 0; i < 4; i++)
#pragma unroll
        for (int rg = 0; rg < 4; rg++)
            gvl[i][rg] = gvs[wy * 64 + i * 16 + quad * 4 + rg];

#pragma unroll
    for (int i = 0; i < 4; i++) {
        const long nodeBase = (blockM + wy * 64 + i * 16) >> 3;
        const int myNode = (int)nodeBase + (quad >> 1);
#pragma unroll
        for (int j = 0; j < 8; j++) {
            float s = 0.f;
#pragma unroll
            for (int rg = 0; rg < 4; rg++) s += acc[i][j][rg] * gvl[i][rg];
            s += __shfl_xor(s, 16, 64);   // combine quad pairs (same node)
            if ((quad & 1) == 0) {
                int col = wxx * 128 + j * 16 + r16;
                EO[(long)r * sEOr + (long)myNode * 256 + col] = f2bf(s);
            }
        }
    }
}

// ---------------------------------------------------------------------------
// LN over (5,512)=2560 + PReLU, in place, bf16. 320 thr, 8 el/thr.
// ---------------------------------------------------------------------------
__global__ __launch_bounds__(320) void ln1_k(
    bf16_t* __restrict__ X, const void* __restrict__ g,
    const void* __restrict__ be, const void* __restrict__ alpha_ptr,
    const int* __restrict__ flag)
{
    const int isbf = *flag;
    const int n = blockIdx.x, t = threadIdx.x;
    bf16_t* row = X + (long)n * 2560;
    const int e0 = t * 8;
    ushort8v xv = *(const ushort8v*)&row[e0];
    float v[8], s = 0.f, sq = 0.f;
#pragma unroll
    for (int k = 0; k < 8; k++) {
        float x = bf2f(xv[k]);
        v[k] = x; s += x; sq += x * x;
    }
    __shared__ float redS[5], redQ[5];
    const int lane = t & 63, wid = t >> 6;
    float ws_ = wave_reduce(s), wq = wave_reduce(sq);
    if (lane == 0) { redS[wid] = ws_; redQ[wid] = wq; }
    __syncthreads();
    float S = 0.f, Q = 0.f;
#pragma unroll
    for (int i = 0; i < 5; i++) { S += redS[i]; Q += redQ[i]; }
    const float mean = S * (1.f / 2560.f);
    const float rstd = rsqrtf(fmaxf(Q * (1.f / 2560.f) - mean * mean, 0.f) + 1e-5f);
    const float alpha = decode_scalar(alpha_ptr, isbf);
    ushort8v gv8 = ld8bf(g, e0, isbf), bv8 = ld8bf(be, e0, isbf);
    ushort8v ov;
#pragma unroll
    for (int k = 0; k < 8; k++) {
        float y = (v[k] - mean) * rstd * bf2f(gv8[k]) + bf2f(bv8[k]);
        ov[k] = f2bf((y >= 0.f) ? y : alpha * y);
    }
    *(ushort8v*)&row[e0] = ov;
}

// ---------------------------------------------------------------------------
// Fused LN2 + PReLU + channel pool (C=5) + global pool (R=2) -> fin [N][512].
// One block per node, 320 threads, 8 el/thr per relation row.
// Wave w <-> channel w (512 el per channel = 64 thr * 8).
// ---------------------------------------------------------------------------
__global__ __launch_bounds__(320) void ln2_gpool_k(
    const bf16_t* __restrict__ X, long sXr, const void* __restrict__ g,
    const void* __restrict__ be, const void* __restrict__ alpha_ptr,
    const void* __restrict__ wr, const void* __restrict__ wg,
    bf16_t* __restrict__ F, const int* __restrict__ flag)
{
    const int isbf = *flag;
    const int n = blockIdx.x, t = threadIdx.x;
    const int lane = t & 63, wid = t >> 6;   // wid == channel
    const int e0 = t * 8;

    __shared__ float hacc[2][512];
    __shared__ float redS[2][5], redQ[2][5], redP[2][5], redG[2][5];
    for (int i = t; i < 1024; i += 320) ((float*)hacc)[i] = 0.f;

    const float alpha = decode_scalar(alpha_ptr, isbf);
    ushort8v gv8 = ld8bf(g, e0, isbf), bv8 = ld8bf(be, e0, isbf);

    for (int r = 0; r < 2; r++) {
        const bf16_t* row = X + (long)r * sXr + (long)n * 2560;
        ushort8v xv = *(const ushort8v*)&row[e0];
        float v[8], s = 0.f, sq = 0.f;
#pragma unroll
        for (int k = 0; k < 8; k++) {
            float x = bf2f(xv[k]);
            v[k] = x; s += x; sq += x * x;
        }
        float ws_ = wave_reduce(s), wq = wave_reduce(sq);
        if (lane == 0) { redS[r][wid] = ws_; redQ[r][wid] = wq; }
        __syncthreads();
        float S = 0.f, Q = 0.f;
#pragma unroll
        for (int i = 0; i < 5; i++) { S += redS[r][i]; Q += redQ[r][i]; }
        const float mean = S * (1.f / 2560.f);
        const float rstd = rsqrtf(fmaxf(Q * (1.f / 2560.f) - mean * mean, 0.f) + 1e-5f);
        float pc = 0.f;
#pragma unroll
        for (int k = 0; k < 8; k++) {
            float y = (v[k] - mean) * rstd * bf2f(gv8[k]) + bf2f(bv8[k]);
            y = (y >= 0.f) ? y : alpha * y;
            v[k] = y;
            pc += y * ld1(wr, (long)r * 512 + ((e0 + k) & 511), isbf);
        }
        float wp = wave_reduce(pc);
        if (lane == 0) redP[r][wid] = wp;
        __syncthreads();
        float ssum = 0.f, eown = 0.f;
#pragma unroll
        for (int c = 0; c < 5; c++) {
            float sg = 1.f / (1.f + expf(-redP[r][c]));
            float e = expf(sg);
            if (c == wid) eown = e;
            ssum += e;
        }
        const float gvc = eown / ssum;
#pragma unroll
        for (int k = 0; k < 8; k++)
            atomicAdd(&hacc[r][(e0 + k) & 511], v[k] * gvc);
        __syncthreads();
    }

    // global pool over R=2
    float pr[2] = {0.f, 0.f};
    for (int h = t; h < 512; h += 320) {
        float w = ld1(wg, h, isbf);
        pr[0] += hacc[0][h] * w;
        pr[1] += hacc[1][h] * w;
    }
#pragma unroll
    for (int r = 0; r < 2; r++) {
        float wp = wave_reduce(pr[r]);
        if (lane == 0) redG[r][wid] = wp;
    }
    __syncthreads();
    float sc0 = 0.f, sc1 = 0.f;
#pragma unroll
    for (int i = 0; i < 5; i++) { sc0 += redG[0][i]; sc1 += redG[1][i]; }
    float eg0 = expf(1.f / (1.f + expf(-sc0)));
    float eg1 = expf(1.f / (1.f + expf(-sc1)));
    float inv = 1.f / (eg0 + eg1);
    for (int h = t; h < 512; h += 320)
        F[(long)n * 512 + h] = f2bf((eg0 * hacc[0][h] + eg1 * hacc[1][h]) * inv);
}

// ---------------------------------------------------------------------------
extern "C" void kernel_launch(void* const* d_in, const int* in_sizes, int n_in,
                              void* d_out, int out_size, void* d_ws, size_t ws_size,
                              hipStream_t stream)
{
    const void* raw   = d_in[0];   // (2,3,16384,256)
    const void* extra = d_in[1];   // (2,1,16384,8,128)
    const void* lbl   = d_in[2];   // (2,1,16384,64)
    const void* femb  = d_in[3];   // (2,3,256,256)
    const void* eemb  = d_in[4];   // (2,1,128,256)
    const void* lemb  = d_in[5];   // (2,1,64,256)
    const void* wx    = d_in[6];   // (1,256)
    const void* wr    = d_in[7];   // (2,512)
    const void* wg    = d_in[8];   // (512,)
    const void* W1    = d_in[9];   // (5,256,512)
    const void* b1    = d_in[10];  // (5,512)
    const void* g1    = d_in[11];
    const void* be1   = d_in[12];
    const void* a1    = d_in[13];
    const void* W2    = d_in[14];  // (5,512,512)
    const void* b2    = d_in[15];
    const void* g2    = d_in[16];
    const void* be2   = d_in[17];
    const void* a2    = d_in[18];
    const void* Wf1   = d_in[19];  // (512,512)
    const void* bf1   = d_in[20];
    const void* af    = d_in[21];
    const void* Wf2   = d_in[22];  // (512,64)
    const void* bf2b  = d_in[23];

    // ---- workspace: flag | transposed bf16 weights | arena ----
    int*    flag  = (int*)d_ws;
    bf16_t* MfT   = (bf16_t*)((char*)d_ws + 256);  // [2][3][512][256]
    bf16_t* MlT   = MfT + 786432;                  // [2][512][64]
    bf16_t* W1c3T = MlT + 65536;                   // [512][256]
    bf16_t* W2T   = W1c3T + 131072;                // [5][512][512]
    bf16_t* Wf1T  = W2T + 1310720;                 // [512][512]
    bf16_t* Wf2T  = Wf1T + 262144;                 // [64][512]
    bf16_t* eT    = Wf2T + 32768;                  // [2][256][128]
    char*   arena = (char*)(eT + 65536);
    const size_t fixedBytes = 256 + 2654208 * 2;

    // per-node arena bytes: x1 2*5120 + x2 2*5120 + eo 2*512 = 21504
    int Nc = 16384;
    while (Nc > 128 && fixedBytes + (size_t)Nc * 21504 > ws_size) Nc >>= 1;
    const int NCH = 16384 / Nc;

    bf16_t* x1 = (bf16_t*)arena;                           // [2][Nc][2560]
    bf16_t* x2 = (bf16_t*)(arena + (size_t)Nc * 10240);    // [2][Nc][2560]
    bf16_t* eo = (bf16_t*)(arena + (size_t)Nc * 20480);    // [2][Nc][256]
    bf16_t* fin = x1;                                      // [Nc][512] alias
    bf16_t* zb  = x1 + (size_t)Nc * 512;                   // [Nc][512] alias

    dim3 blk(256), blk5(320);

    detect_k<<<1, 64, 0, stream>>>((const unsigned int*)raw,
                                   (long)in_sizes[0] / 2, flag);

    // ---- weight transposes (bf16 [N][K]) ----
    transT_k<<<dim3(1024, 1, 5), blk, 0, stream>>>(W2, 0, 262144, 512, 512,
                                                   W2T, 0, 262144, flag);
    transT_k<<<dim3(512, 1, 1), blk, 0, stream>>>(W1, 3L * 131072, 0, 256, 512,
                                                  W1c3T, 0, 0, flag);
    transT_k<<<dim3(1024, 1, 1), blk, 0, stream>>>(Wf1, 0, 0, 512, 512,
                                                   Wf1T, 0, 0, flag);
    transT_k<<<dim3(128, 1, 1), blk, 0, stream>>>(Wf2, 0, 0, 512, 64,
                                                  Wf2T, 0, 0, flag);
    transT_k<<<dim3(128, 1, 2), blk, 0, stream>>>(eemb, 0, 32768, 128, 256,
                                                  eT, 0, 32768, flag);

    // ---- folds: MfT[r,k] = (femb[r,k]@W1[k])^T, MlT[r] = (lemb[r]@W1[4])^T
    for (int r = 0; r < 2; r++) {
        fold_gemmT_k<<<dim3(8, 4, 3), blk, 0, stream>>>(
            femb, (long)r * 196608, 65536, 256,
            W1, 0, 131072, 512,
            MfT, (long)r * 393216, 131072, 256, 256, flag);
    }
    fold_gemmT_k<<<dim3(8, 1, 2), blk, 0, stream>>>(
        lemb, 0, 16384, 256,
        W1, 4L * 131072, 0, 512,
        MlT, 0, 32768, 64, 256, flag);

    for (int c = 0; c < NCH; c++) {
        const long n0 = (long)c * Nc;

        // fused extra GEMM + pool -> eo bf16 [2][Nc][256]
        megemm_pool<<<dim3(1, Nc / 16, 2), blk, 0, stream>>>(
            extra, n0 * 1024, 16777216,
            eT, 32768, wx, eo, (long)Nc * 256, flag);

        // x1 ch0..2 (both relations): z=r*3+k
        mgemm<128, 64, 1, 1><<<dim3(4, Nc / 128, 6), blk, 0, stream>>>(
            raw, 2, n0 * 256, 12582912, 4194304, 256,
            MfT, 0, 393216, 131072,
            x1, 0, (long)Nc * 2560, 512, 2560,
            b1, 0, 0, 512, nullptr, 256, 3, flag);
        // x1 ch3 = eo[r] @ W1c3T^T + b1[3]
        mgemm<128, 64, 1, 1><<<dim3(4, Nc / 128, 2), blk, 0, stream>>>(
            eo, 1, 0, (long)Nc * 256, 0, 256,
            W1c3T, 0, 0, 0,
            x1, 3L * 512, (long)Nc * 2560, 0, 2560,
            b1, 3L * 512, 0, 0, nullptr, 256, 1, flag);
        // x1 ch4 = lbl[r,chunk] @ MlT[r]^T + b1[4]
        mgemm<128, 64, 1, 1><<<dim3(4, Nc / 128, 2), blk, 0, stream>>>(
            lbl, 2, n0 * 64, 1048576, 0, 64,
            MlT, 0, 32768, 0,
            x1, 4L * 512, (long)Nc * 2560, 0, 2560,
            b1, 4L * 512, 0, 0, nullptr, 64, 1, flag);

        // LN1 + PReLU in place (both relations)
        ln1_k<<<2 * Nc, blk5, 0, stream>>>(x1, g1, be1, a1, flag);

        // x2[r][:,ch,:] = x1[r][:,ch,:] @ W2T[ch]^T + b2[ch]: z=r*5+ch
        mgemm<128, 64, 1, 1><<<dim3(4, Nc / 128, 10), blk, 0, stream>>>(
            x1, 1, 0, (long)Nc * 2560, 512, 2560,
            W2T, 0, 0, 262144,
            x2, 0, (long)Nc * 2560, 512, 2560,
            b2, 0, 0, 512, nullptr, 512, 5, flag);

        // fused LN2 + channel pool + global pool -> fin [Nc][512]
        ln2_gpool_k<<<Nc, blk5, 0, stream>>>(
            x2, (long)Nc * 2560, g2, be2, a2, wr, wg, fin, flag);

        // z = PReLU(fin @ Wf1T^T + bf1)
        mgemm<128, 64, 2, 1><<<dim3(4, Nc / 128, 1), blk, 0, stream>>>(
            fin, 1, 0, 0, 0, 512,
            Wf1T, 0, 0, 0,
            zb, 0, 0, 0, 512,
            bf1, 0, 0, 0, af, 512, 1, flag);
        // out = z @ Wf2T^T + bf2
        mgemm<64, 32, 1, 2><<<dim3(1, Nc / 128, 1), blk, 0, stream>>>(
            zb, 1, 0, 0, 0, 512,
            Wf2T, 0, 0, 0,
            d_out, n0 * 64, 0, 0, 64,
            bf2b, 0, 0, 0, nullptr, 512, 1, flag);
    }
}